// Round 14
// baseline (208.725 us; speedup 1.0000x reference)
//
#include <hip/hip_runtime.h>
#include <math.h>

typedef __bf16 bf16;
typedef __attribute__((ext_vector_type(8))) __bf16 bf16x8;
typedef __attribute__((ext_vector_type(4))) float f32x4;
typedef __attribute__((ext_vector_type(8))) int i32x8;

typedef __attribute__((address_space(1))) const void gvoid;
typedef __attribute__((address_space(3))) void lvoid;
#define GLL(g, l) __builtin_amdgcn_global_load_lds((gvoid*)(g), (lvoid*)(l), 16, 0, 0)
#define MFMA(a, b, c) __builtin_amdgcn_mfma_f32_16x16x32_bf16((a), (b), (c), 0, 0, 0)
// MX-scaled fp8 GEMM, unit scales (E8M0 0x7F = 1.0): exact same math as fp8_fp8, 2.28x rate
#define MFMAS(a, b, c) \
  __builtin_amdgcn_mfma_scale_f32_16x16x128_f8f6f4((a), (b), (c), 0, 0, 0, 0x7F, 0, 0x7F)

__device__ __forceinline__ int swz128(int row, int kb) { return kb ^ ((row & 7) << 4); }

// ---- fp8 e4m3fn encode/decode (OCP: bias 7, max 448, no inf) ----
__device__ __forceinline__ unsigned char f32_to_e4m3(float x) {
  const unsigned s = (__float_as_uint(x) >> 24) & 0x80;
  float ax = fminf(fabsf(x), 448.f);
  unsigned e;
  if (ax >= 0.015625f) {  // normal range (>= 2^-6)
    const unsigned u = __float_as_uint(ax);
    const unsigned t = u + 0x7FFFF + ((u >> 20) & 1);  // RNE to 3 mantissa bits
    e = (((t >> 23) - 120) << 3) | ((t >> 20) & 7);
  } else {  // subnormal: value = q * 2^-9, q in 0..8
    e = (unsigned)__float2int_rn(ax * 512.f);
  }
  return (unsigned char)(s | e);
}
__device__ __forceinline__ float e4m3_to_f32(unsigned char b) {
  const unsigned s = ((unsigned)b & 0x80) << 24;
  const unsigned em = b & 0x7F;
  float v;
  if (em >= 8) v = __uint_as_float((((em >> 3) + 120) << 23) | ((em & 7) << 20));
  else v = (float)em * 0.001953125f;
  return __uint_as_float(__float_as_uint(v) | s);
}

// ---------------- prep: W1 [1024][512] -> W1t bf16 [512][1024]; W2 [512][256] -> W2t [256][512]
__global__ __launch_bounds__(256) void prep_w(const float* __restrict__ W1,
                                              const float* __restrict__ W2,
                                              bf16* __restrict__ W1t, bf16* __restrict__ W2t) {
  const int t = blockIdx.x * 256 + threadIdx.x;
  if (t < 512 * 1024) {
    const int h = t & 511, k = t >> 9;
    W1t[h * 1024 + k] = (bf16)W1[k * 512 + h];
  } else {
    const int u = t - 512 * 1024;
    const int e = u & 255, k = u >> 8;
    W2t[e * 512 + k] = (bf16)W2[k * 256 + e];
  }
}

// ---------------- prep: bank fp32 [16384][256] -> SB8 = e4m3(-2*bank) repacked as a
// per-(tile, wave, half, lane) register-fragment stream:
//   SB8[(((t*8+w)*2+h)*64 + lk*16 + lr)*32 + (k & 31)]  holds bank row (t*128+w*16+lr),
//   k = h*128 + lk*32 + [0,32)  -- one i32x8 load per lane per half, fully coalesced.
// m2[row] consistent with the quantized values used in MFMA.
__global__ __launch_bounds__(256) void prep_bank(const float* __restrict__ bank,
                                                 unsigned char* __restrict__ SB8,
                                                 float* __restrict__ m2) {
  const int tid = threadIdx.x, lane = tid & 63, wv = tid >> 6;
  const int row = blockIdx.x * 4 + wv;
  const float4 v = *reinterpret_cast<const float4*>(bank + (size_t)row * 256 + lane * 4);
  uchar4 q;
  float ssum = 0.f;
  {
    const float xs[4] = {v.x, v.y, v.z, v.w};
    unsigned char qb[4];
#pragma unroll
    for (int e = 0; e < 4; ++e) {
      qb[e] = f32_to_e4m3(-2.f * xs[e]);
      const float d = e4m3_to_f32(qb[e]);
      ssum += d * d;
    }
    q.x = qb[0]; q.y = qb[1]; q.z = qb[2]; q.w = qb[3];
  }
#pragma unroll
  for (int off = 1; off < 64; off <<= 1) ssum += __shfl_xor(ssum, off);
  // k0 = lane*4: h = k0>>7, lk = (k0>>5)&3, off32 = k0&31
  const int t = row >> 7, ww = (row >> 4) & 7, lrr = row & 15;
  const int h = lane >> 5, lk = (lane >> 3) & 3, off32 = (lane & 7) * 4;
  const size_t dst = ((((size_t)t * 8 + ww) * 2 + h) * 64 + lk * 16 + lrr) * 32 + off32;
  *reinterpret_cast<uchar4*>(SB8 + dst) = q;
  if (lane == 0) m2[row] = ssum * 0.25f;  // (d/2)^2 summed
}

// ---------------- mlp1: H[32768][512] = relu(F @ W1 + b1), bf16 out
__global__ __launch_bounds__(512, 2) void mlp1_kernel(const float* __restrict__ F,
                                                      const bf16* __restrict__ W1t,
                                                      const float* __restrict__ b1,
                                                      bf16* __restrict__ H) {
  __shared__ __align__(16) char smem[81920];
  char* sA = smem;          // F chunk bf16 [128 rows][128B], swizzled
  char* sB = smem + 16384;  // W1t chunk [512 n][128B], swizzled

  const int tid = threadIdx.x;
  const int w = tid >> 6, lane = tid & 63;
  const int wm = w >> 2, wn = w & 3;
  const int lr = lane & 15, lk = lane >> 4;
  const size_t r0 = (size_t)blockIdx.x * 128;

  f32x4 acc[4][8];
  const f32x4 z = {0.f, 0.f, 0.f, 0.f};
#pragma unroll
  for (int m = 0; m < 4; ++m)
#pragma unroll
    for (int n = 0; n < 8; ++n) acc[m][n] = z;

  for (int kc = 0; kc < 16; ++kc) {
    {
      const int fr = tid >> 2, kg = (tid & 3) << 4;
      const float* fsrc = F + (r0 + fr) * 1024 + kc * 64 + kg;
      const float4 f0 = *reinterpret_cast<const float4*>(fsrc);
      const float4 f1 = *reinterpret_cast<const float4*>(fsrc + 4);
      const float4 f2 = *reinterpret_cast<const float4*>(fsrc + 8);
      const float4 f3 = *reinterpret_cast<const float4*>(fsrc + 12);
      bf16x8 p0, p1;
      p0[0] = (bf16)f0.x; p0[1] = (bf16)f0.y; p0[2] = (bf16)f0.z; p0[3] = (bf16)f0.w;
      p0[4] = (bf16)f1.x; p0[5] = (bf16)f1.y; p0[6] = (bf16)f1.z; p0[7] = (bf16)f1.w;
      p1[0] = (bf16)f2.x; p1[1] = (bf16)f2.y; p1[2] = (bf16)f2.z; p1[3] = (bf16)f2.w;
      p1[4] = (bf16)f3.x; p1[5] = (bf16)f3.y; p1[6] = (bf16)f3.z; p1[7] = (bf16)f3.w;
      const int bb = kg * 2;
      *(bf16x8*)(sA + fr * 128 + swz128(fr, bb)) = p0;
      *(bf16x8*)(sA + fr * 128 + swz128(fr, bb + 16)) = p1;
    }
#pragma unroll
    for (int i = 0; i < 8; ++i) {
      const int o = (w * 8 + i) * 1024 + lane * 16;
      const int n = o >> 7, b = o & 127;
      GLL((const char*)W1t + n * 2048 + kc * 128 + swz128(n, b), sB + (w * 8 + i) * 1024);
    }
    __syncthreads();
#pragma unroll
    for (int ks = 0; ks < 2; ++ks) {
      bf16x8 av[4];
#pragma unroll
      for (int Mt = 0; Mt < 4; ++Mt) {
        const int row = wm * 64 + Mt * 16 + lr;
        av[Mt] = *(const bf16x8*)(sA + row * 128 + swz128(row, ks * 64 + lk * 16));
      }
#pragma unroll
      for (int Nt = 0; Nt < 8; ++Nt) {
        const int n = wn * 128 + Nt * 16 + lr;
        const bf16x8 bv = *(const bf16x8*)(sB + n * 128 + swz128(n, ks * 64 + lk * 16));
#pragma unroll
        for (int Mt = 0; Mt < 4; ++Mt) acc[Mt][Nt] = MFMA(av[Mt], bv, acc[Mt][Nt]);
      }
    }
    __syncthreads();
  }
#pragma unroll
  for (int Nt = 0; Nt < 8; ++Nt) {
    const int col = wn * 128 + Nt * 16 + lr;
    const float bias = b1[col];
#pragma unroll
    for (int Mt = 0; Mt < 4; ++Mt) {
      const size_t rowb = r0 + wm * 64 + Mt * 16 + lk * 4;
#pragma unroll
      for (int q = 0; q < 4; ++q)
        H[(rowb + q) * 512 + col] = (bf16)fmaxf(acc[Mt][Nt][q] + bias, 0.f);
    }
  }
}

// ---------------- mlp2: PROJ8[32768][256] fp8 = e4m3(H @ W2 + b2); X2 from decoded fp8
__global__ __launch_bounds__(512, 2) void mlp2_kernel(const bf16* __restrict__ H,
                                                      const bf16* __restrict__ W2t,
                                                      const float* __restrict__ b2,
                                                      unsigned char* __restrict__ PROJ8,
                                                      float* __restrict__ X2) {
  __shared__ __align__(16) char smem[51200];
  char* sA = smem;                        // H chunk [128][128B] swizzled
  char* sB = smem + 16384;                // W2t chunk [256][128B] swizzled
  float* sX2 = (float*)(smem + 49152);    // [4][128]

  const int tid = threadIdx.x;
  const int w = tid >> 6, lane = tid & 63;
  const int wm = w >> 2, wn = w & 3;
  const int lr = lane & 15, lk = lane >> 4;
  const size_t r0 = (size_t)blockIdx.x * 128;

  f32x4 acc[4][4];
  const f32x4 z = {0.f, 0.f, 0.f, 0.f};
#pragma unroll
  for (int m = 0; m < 4; ++m)
#pragma unroll
    for (int n = 0; n < 4; ++n) acc[m][n] = z;

  for (int kc = 0; kc < 8; ++kc) {
#pragma unroll
    for (int i = 0; i < 2; ++i) {
      const int o = (w * 2 + i) * 1024 + lane * 16;
      const int row = o >> 7, b = o & 127;
      GLL((const char*)H + (r0 + row) * 1024 + kc * 128 + swz128(row, b), sA + (w * 2 + i) * 1024);
    }
#pragma unroll
    for (int i = 0; i < 4; ++i) {
      const int o = (w * 4 + i) * 1024 + lane * 16;
      const int n = o >> 7, b = o & 127;
      GLL((const char*)W2t + n * 1024 + kc * 128 + swz128(n, b), sB + (w * 4 + i) * 1024);
    }
    __syncthreads();
#pragma unroll
    for (int ks = 0; ks < 2; ++ks) {
      bf16x8 av[4];
#pragma unroll
      for (int Mt = 0; Mt < 4; ++Mt) {
        const int row = wm * 64 + Mt * 16 + lr;
        av[Mt] = *(const bf16x8*)(sA + row * 128 + swz128(row, ks * 64 + lk * 16));
      }
#pragma unroll
      for (int Nt = 0; Nt < 4; ++Nt) {
        const int n = wn * 64 + Nt * 16 + lr;
        const bf16x8 bv = *(const bf16x8*)(sB + n * 128 + swz128(n, ks * 64 + lk * 16));
#pragma unroll
        for (int Mt = 0; Mt < 4; ++Mt) acc[Mt][Nt] = MFMA(av[Mt], bv, acc[Mt][Nt]);
      }
    }
    __syncthreads();
  }
  // epilogue: +b2, quantize to fp8, store PROJ8, accumulate consistent x2
  float x2p[4][4];
#pragma unroll
  for (int m = 0; m < 4; ++m)
#pragma unroll
    for (int q = 0; q < 4; ++q) x2p[m][q] = 0.f;
#pragma unroll
  for (int Nt = 0; Nt < 4; ++Nt) {
    const int col = wn * 64 + Nt * 16 + lr;
    const float bias = b2[col];
#pragma unroll
    for (int Mt = 0; Mt < 4; ++Mt) {
      const size_t rowb = r0 + wm * 64 + Mt * 16 + lk * 4;
#pragma unroll
      for (int q = 0; q < 4; ++q) {
        const float p = acc[Mt][Nt][q] + bias;
        const unsigned char qb = f32_to_e4m3(p);
        PROJ8[(rowb + q) * 256 + col] = qb;
        const float d = e4m3_to_f32(qb);
        x2p[Mt][q] += d * d;
      }
    }
  }
#pragma unroll
  for (int Mt = 0; Mt < 4; ++Mt)
#pragma unroll
    for (int q = 0; q < 4; ++q) {
      float v = x2p[Mt][q];
      v += __shfl_xor(v, 1); v += __shfl_xor(v, 2);
      v += __shfl_xor(v, 4); v += __shfl_xor(v, 8);
      x2p[Mt][q] = v;
    }
  __syncthreads();
  if (lr == 0) {
#pragma unroll
    for (int Mt = 0; Mt < 4; ++Mt)
#pragma unroll
      for (int q = 0; q < 4; ++q)
        sX2[wn * 128 + wm * 64 + Mt * 16 + lk * 4 + q] = x2p[Mt][q];
  }
  __syncthreads();
  if (tid < 128)
    X2[r0 + tid] = sX2[tid] + sX2[128 + tid] + sX2[256 + tid] + sX2[384 + tid];
}

// ---------------- dist (MX-fp8, LDS-free): Mt=8 (128 rows/block, grid 256 = 1 block/CU,
// L2 traffic 30 B/cyc/CU << 56 ceiling), depth-2 named ring (238/256 regs: r8/r10 lesson
// -- keep slack). NO sched_barrier (m141: pinning defeats the scheduler); compiler
// interleaves load issue into the MFMA stream with counted waitcnts. acc init folded into
// the first MFMA's C operand (4 movs instead of 32). Tiles 128/129 loaded but never used.
__global__ __launch_bounds__(512, 2) void dist_kernel(const unsigned char* __restrict__ PROJ8,
                                                      const unsigned char* __restrict__ SB8,
                                                      const float* __restrict__ m2g,
                                                      const float* __restrict__ X2,
                                                      float* __restrict__ out) {
  __shared__ float minbuf[1024];  // [8 waves][128 rows]

  const int tid = threadIdx.x;
  const int w = tid >> 6, lane = tid & 63;
  const int lr = lane & 15, lk = lane >> 4;
  const size_t r0 = (size_t)blockIdx.x * 128;

  // A fragments: A[Mt][h] = 32 fp8 of proj row (r0+Mt*16+lr), k = h*128 + lk*32 .. +32
  i32x8 A[8][2];
#pragma unroll
  for (int Mt = 0; Mt < 8; ++Mt)
#pragma unroll
    for (int h = 0; h < 2; ++h)
      A[Mt][h] = *(const i32x8*)(PROJ8 + (r0 + Mt * 16 + lr) * 256 + h * 128 + lk * 32);

  const char* sb = (const char*)SB8 + ((size_t)w * 2 * 64 + lane) * 32;  // + t*32768, h*2048
  const float* m2p = m2g + w * 16 + lr;                                  // + t*128

  f32x4 minv[8];
#pragma unroll
  for (int Mt = 0; Mt < 8; ++Mt)
#pragma unroll
    for (int q = 0; q < 4; ++q) minv[Mt][q] = 3.0e38f;

#define LOADT(B0, B1, MC, tt)                                \
  do {                                                       \
    B0 = *(const i32x8*)(sb + (size_t)(tt) * 32768);         \
    B1 = *(const i32x8*)(sb + (size_t)(tt) * 32768 + 2048);  \
    MC = m2p[(tt) * 128];                                    \
  } while (0)

  // acc starts at m2[col] (via the C operand of the first MFMA); SB8 = -2*bank,
  // so acc ends at m2 - 2*<proj,bank>.
#define COMPUTE(B0, B1, MC)                                                       \
  do {                                                                            \
    f32x4 mv;                                                                     \
    mv[0] = (MC); mv[1] = (MC); mv[2] = (MC); mv[3] = (MC);                       \
    f32x4 acc[8];                                                                 \
    __builtin_amdgcn_s_setprio(1);                                                \
    _Pragma("unroll") for (int Mt = 0; Mt < 8; ++Mt)                              \
      acc[Mt] = MFMAS(A[Mt][0], (B0), mv);                                        \
    _Pragma("unroll") for (int Mt = 0; Mt < 8; ++Mt)                              \
      acc[Mt] = MFMAS(A[Mt][1], (B1), acc[Mt]);                                   \
    __builtin_amdgcn_s_setprio(0);                                                \
    _Pragma("unroll") for (int Mt = 0; Mt < 8; ++Mt) {                            \
      minv[Mt][0] = fminf(minv[Mt][0], acc[Mt][0]);                               \
      minv[Mt][1] = fminf(minv[Mt][1], acc[Mt][1]);                               \
      minv[Mt][2] = fminf(minv[Mt][2], acc[Mt][2]);                               \
      minv[Mt][3] = fminf(minv[Mt][3], acc[Mt][3]);                               \
    }                                                                             \
  } while (0)

  // prologue: preload tiles 0,1 into slots a,b
  i32x8 a0, a1, b0, b1;
  float ma, mb;
  LOADT(a0, a1, ma, 0);
  LOADT(b0, b1, mb, 1);

  for (int t = 0; t < 128; t += 2) {
    COMPUTE(a0, a1, ma);
    LOADT(a0, a1, ma, t + 2);
    COMPUTE(b0, b1, mb);
    LOADT(b0, b1, mb, t + 3);
  }
#undef LOADT
#undef COMPUTE

  // reduce min over the 16 bank-column lanes (lr); rows live at lk*4+q
#pragma unroll
  for (int Mt = 0; Mt < 8; ++Mt)
#pragma unroll
    for (int q = 0; q < 4; ++q) {
      float v = minv[Mt][q];
      v = fminf(v, __shfl_xor(v, 1)); v = fminf(v, __shfl_xor(v, 2));
      v = fminf(v, __shfl_xor(v, 4)); v = fminf(v, __shfl_xor(v, 8));
      minv[Mt][q] = v;
    }
  if (lr == 0) {
#pragma unroll
    for (int Mt = 0; Mt < 8; ++Mt)
#pragma unroll
      for (int q = 0; q < 4; ++q)
        minbuf[w * 128 + Mt * 16 + lk * 4 + q] = minv[Mt][q];
  }
  __syncthreads();
  if (tid < 128) {
    float m = minbuf[tid];
#pragma unroll
    for (int v = 1; v < 8; ++v) m = fminf(m, minbuf[v * 128 + tid]);
    const float d2 = X2[r0 + tid] + m;
    out[r0 + tid] = sqrtf(fmaxf(d2, 0.f));
  }
}

extern "C" void kernel_launch(void* const* d_in, const int* in_sizes, int n_in,
                              void* d_out, int out_size, void* d_ws, size_t ws_size,
                              hipStream_t stream) {
  const float* F = (const float*)d_in[0];
  const float* W1 = (const float*)d_in[1];
  const float* b1 = (const float*)d_in[2];
  const float* W2 = (const float*)d_in[3];
  const float* b2 = (const float*)d_in[4];
  const float* bank = (const float*)d_in[5];
  float* out = (float*)d_out;

  char* ws = (char*)d_ws;
  unsigned char* SB8 = (unsigned char*)(ws + 0);   // 4,194,304 B + 131,072 pad (read-only pad)
  float* m2 = (float*)(ws + 4325376);              //    65,536 B +   2,048 pad (read-only pad)
  bf16* W1t = (bf16*)(ws + 4392960);               // 1,048,576 B
  bf16* W2t = (bf16*)(ws + 5441536);               //   262,144 B
  bf16* H = (bf16*)(ws + 5703680);                 // 33,554,432 B
  unsigned char* PROJ8 = (unsigned char*)(ws + 39258112);  // 8,388,608 B
  float* X2 = (float*)(ws + 47646720);             //   131,072 B -> total 47,777,792 B

  prep_w<<<2560, 256, 0, stream>>>(W1, W2, W1t, W2t);
  prep_bank<<<4096, 256, 0, stream>>>(bank, SB8, m2);
  mlp1_kernel<<<256, 512, 0, stream>>>(F, W1t, b1, H);
  mlp2_kernel<<<256, 512, 0, stream>>>(H, W2t, b2, PROJ8, X2);
  dist_kernel<<<256, 512, 0, stream>>>(PROJ8, SB8, m2, X2, out);
}

// Round 15
// 204.411 us; speedup vs baseline: 1.0211x; 1.0211x over previous
//
#include <hip/hip_runtime.h>
#include <math.h>

typedef __bf16 bf16;
typedef __attribute__((ext_vector_type(8))) __bf16 bf16x8;
typedef __attribute__((ext_vector_type(4))) float f32x4;
typedef __attribute__((ext_vector_type(16))) float f32x16;
typedef __attribute__((ext_vector_type(8))) int i32x8;

typedef __attribute__((address_space(1))) const void gvoid;
typedef __attribute__((address_space(3))) void lvoid;
#define GLL(g, l) __builtin_amdgcn_global_load_lds((gvoid*)(g), (lvoid*)(l), 16, 0, 0)
#define MFMA(a, b, c) __builtin_amdgcn_mfma_f32_16x16x32_bf16((a), (b), (c), 0, 0, 0)
// MX-scaled fp8 GEMM 32x32x64, unit scales (E8M0 0x7F = 1.0): same math as fp8, ~4.7 PF rate
#define MFMAS32(a, b, c) \
  __builtin_amdgcn_mfma_scale_f32_32x32x64_f8f6f4((a), (b), (c), 0, 0, 0, 0x7F, 0, 0x7F)

__device__ __forceinline__ int swz128(int row, int kb) { return kb ^ ((row & 7) << 4); }

// ---- fp8 e4m3fn encode/decode (OCP: bias 7, max 448, no inf) ----
__device__ __forceinline__ unsigned char f32_to_e4m3(float x) {
  const unsigned s = (__float_as_uint(x) >> 24) & 0x80;
  float ax = fminf(fabsf(x), 448.f);
  unsigned e;
  if (ax >= 0.015625f) {  // normal range (>= 2^-6)
    const unsigned u = __float_as_uint(ax);
    const unsigned t = u + 0x7FFFF + ((u >> 20) & 1);  // RNE to 3 mantissa bits
    e = (((t >> 23) - 120) << 3) | ((t >> 20) & 7);
  } else {  // subnormal: value = q * 2^-9, q in 0..8
    e = (unsigned)__float2int_rn(ax * 512.f);
  }
  return (unsigned char)(s | e);
}
__device__ __forceinline__ float e4m3_to_f32(unsigned char b) {
  const unsigned s = ((unsigned)b & 0x80) << 24;
  const unsigned em = b & 0x7F;
  float v;
  if (em >= 8) v = __uint_as_float((((em >> 3) + 120) << 23) | ((em & 7) << 20));
  else v = (float)em * 0.001953125f;
  return __uint_as_float(__float_as_uint(v) | s);
}

// ---------------- merged prep (one launch):
// blocks [0,2560): W1 [1024][512] -> W1t bf16 [512][1024]; W2 [512][256] -> W2t [256][512]
// blocks [2560,6656): bank fp32 [16384][256] -> SB8 = e4m3(-2*bank) repacked as the
//   32x32x64 register-fragment stream:
//   SB8[((t*4+bg)*4 + kc4)*2048 + (hi*32 + l31)*32 + j] holds bank row (t*128+bg*32+l31),
//   k = kc4*64 + hi*32 + j  -- one i32x8 per (lane, kc4), fully coalesced.
//   m2[row] consistent with the quantized values used in MFMA.
__global__ __launch_bounds__(256) void prep_all(const float* __restrict__ W1,
                                                const float* __restrict__ W2,
                                                const float* __restrict__ bank,
                                                bf16* __restrict__ W1t, bf16* __restrict__ W2t,
                                                unsigned char* __restrict__ SB8,
                                                float* __restrict__ m2) {
  const int blk = blockIdx.x;
  if (blk < 2560) {
    const int t = blk * 256 + threadIdx.x;
    if (t < 512 * 1024) {
      const int h = t & 511, k = t >> 9;
      W1t[h * 1024 + k] = (bf16)W1[k * 512 + h];
    } else {
      const int u = t - 512 * 1024;
      const int e = u & 255, k = u >> 8;
      W2t[e * 512 + k] = (bf16)W2[k * 256 + e];
    }
    return;
  }
  const int tid = threadIdx.x, lane = tid & 63, wv = tid >> 6;
  const int row = (blk - 2560) * 4 + wv;
  const float4 v = *reinterpret_cast<const float4*>(bank + (size_t)row * 256 + lane * 4);
  uchar4 q;
  float ssum = 0.f;
  {
    const float xs[4] = {v.x, v.y, v.z, v.w};
    unsigned char qb[4];
#pragma unroll
    for (int e = 0; e < 4; ++e) {
      qb[e] = f32_to_e4m3(-2.f * xs[e]);
      const float d = e4m3_to_f32(qb[e]);
      ssum += d * d;
    }
    q.x = qb[0]; q.y = qb[1]; q.z = qb[2]; q.w = qb[3];
  }
#pragma unroll
  for (int off = 1; off < 64; off <<= 1) ssum += __shfl_xor(ssum, off);
  const int k0 = lane * 4;
  const int t = row >> 7, bg = (row >> 5) & 3, l31 = row & 31;
  const int kc4 = k0 >> 6, hi = (k0 >> 5) & 1, j = k0 & 31;
  const size_t dst = (size_t)((t * 4 + bg) * 4 + kc4) * 2048 + (hi * 32 + l31) * 32 + j;
  *reinterpret_cast<uchar4*>(SB8 + dst) = q;
  if (lane == 0) m2[row] = ssum * 0.25f;  // (d/2)^2 summed
}

// ---------------- mlp1: H[32768][512] = relu(F @ W1 + b1), bf16 out
__global__ __launch_bounds__(512, 2) void mlp1_kernel(const float* __restrict__ F,
                                                      const bf16* __restrict__ W1t,
                                                      const float* __restrict__ b1,
                                                      bf16* __restrict__ H) {
  __shared__ __align__(16) char smem[81920];
  char* sA = smem;          // F chunk bf16 [128 rows][128B], swizzled
  char* sB = smem + 16384;  // W1t chunk [512 n][128B], swizzled

  const int tid = threadIdx.x;
  const int w = tid >> 6, lane = tid & 63;
  const int wm = w >> 2, wn = w & 3;
  const int lr = lane & 15, lk = lane >> 4;
  const size_t r0 = (size_t)blockIdx.x * 128;

  f32x4 acc[4][8];
  const f32x4 z = {0.f, 0.f, 0.f, 0.f};
#pragma unroll
  for (int m = 0; m < 4; ++m)
#pragma unroll
    for (int n = 0; n < 8; ++n) acc[m][n] = z;

  for (int kc = 0; kc < 16; ++kc) {
    {
      const int fr = tid >> 2, kg = (tid & 3) << 4;
      const float* fsrc = F + (r0 + fr) * 1024 + kc * 64 + kg;
      const float4 f0 = *reinterpret_cast<const float4*>(fsrc);
      const float4 f1 = *reinterpret_cast<const float4*>(fsrc + 4);
      const float4 f2 = *reinterpret_cast<const float4*>(fsrc + 8);
      const float4 f3 = *reinterpret_cast<const float4*>(fsrc + 12);
      bf16x8 p0, p1;
      p0[0] = (bf16)f0.x; p0[1] = (bf16)f0.y; p0[2] = (bf16)f0.z; p0[3] = (bf16)f0.w;
      p0[4] = (bf16)f1.x; p0[5] = (bf16)f1.y; p0[6] = (bf16)f1.z; p0[7] = (bf16)f1.w;
      p1[0] = (bf16)f2.x; p1[1] = (bf16)f2.y; p1[2] = (bf16)f2.z; p1[3] = (bf16)f2.w;
      p1[4] = (bf16)f3.x; p1[5] = (bf16)f3.y; p1[6] = (bf16)f3.z; p1[7] = (bf16)f3.w;
      const int bb = kg * 2;
      *(bf16x8*)(sA + fr * 128 + swz128(fr, bb)) = p0;
      *(bf16x8*)(sA + fr * 128 + swz128(fr, bb + 16)) = p1;
    }
#pragma unroll
    for (int i = 0; i < 8; ++i) {
      const int o = (w * 8 + i) * 1024 + lane * 16;
      const int n = o >> 7, b = o & 127;
      GLL((const char*)W1t + n * 2048 + kc * 128 + swz128(n, b), sB + (w * 8 + i) * 1024);
    }
    __syncthreads();
#pragma unroll
    for (int ks = 0; ks < 2; ++ks) {
      bf16x8 av[4];
#pragma unroll
      for (int Mt = 0; Mt < 4; ++Mt) {
        const int row = wm * 64 + Mt * 16 + lr;
        av[Mt] = *(const bf16x8*)(sA + row * 128 + swz128(row, ks * 64 + lk * 16));
      }
#pragma unroll
      for (int Nt = 0; Nt < 8; ++Nt) {
        const int n = wn * 128 + Nt * 16 + lr;
        const bf16x8 bv = *(const bf16x8*)(sB + n * 128 + swz128(n, ks * 64 + lk * 16));
#pragma unroll
        for (int Mt = 0; Mt < 4; ++Mt) acc[Mt][Nt] = MFMA(av[Mt], bv, acc[Mt][Nt]);
      }
    }
    __syncthreads();
  }
#pragma unroll
  for (int Nt = 0; Nt < 8; ++Nt) {
    const int col = wn * 128 + Nt * 16 + lr;
    const float bias = b1[col];
#pragma unroll
    for (int Mt = 0; Mt < 4; ++Mt) {
      const size_t rowb = r0 + wm * 64 + Mt * 16 + lk * 4;
#pragma unroll
      for (int q = 0; q < 4; ++q)
        H[(rowb + q) * 512 + col] = (bf16)fmaxf(acc[Mt][Nt][q] + bias, 0.f);
    }
  }
}

// ---------------- mlp2: PROJ8[32768][256] fp8 = e4m3(H @ W2 + b2); X2 from decoded fp8
__global__ __launch_bounds__(512, 2) void mlp2_kernel(const bf16* __restrict__ H,
                                                      const bf16* __restrict__ W2t,
                                                      const float* __restrict__ b2,
                                                      unsigned char* __restrict__ PROJ8,
                                                      float* __restrict__ X2) {
  __shared__ __align__(16) char smem[51200];
  char* sA = smem;                        // H chunk [128][128B] swizzled
  char* sB = smem + 16384;                // W2t chunk [256][128B] swizzled
  float* sX2 = (float*)(smem + 49152);    // [4][128]

  const int tid = threadIdx.x;
  const int w = tid >> 6, lane = tid & 63;
  const int wm = w >> 2, wn = w & 3;
  const int lr = lane & 15, lk = lane >> 4;
  const size_t r0 = (size_t)blockIdx.x * 128;

  f32x4 acc[4][4];
  const f32x4 z = {0.f, 0.f, 0.f, 0.f};
#pragma unroll
  for (int m = 0; m < 4; ++m)
#pragma unroll
    for (int n = 0; n < 4; ++n) acc[m][n] = z;

  for (int kc = 0; kc < 8; ++kc) {
#pragma unroll
    for (int i = 0; i < 2; ++i) {
      const int o = (w * 2 + i) * 1024 + lane * 16;
      const int row = o >> 7, b = o & 127;
      GLL((const char*)H + (r0 + row) * 1024 + kc * 128 + swz128(row, b), sA + (w * 2 + i) * 1024);
    }
#pragma unroll
    for (int i = 0; i < 4; ++i) {
      const int o = (w * 4 + i) * 1024 + lane * 16;
      const int n = o >> 7, b = o & 127;
      GLL((const char*)W2t + n * 1024 + kc * 128 + swz128(n, b), sB + (w * 4 + i) * 1024);
    }
    __syncthreads();
#pragma unroll
    for (int ks = 0; ks < 2; ++ks) {
      bf16x8 av[4];
#pragma unroll
      for (int Mt = 0; Mt < 4; ++Mt) {
        const int row = wm * 64 + Mt * 16 + lr;
        av[Mt] = *(const bf16x8*)(sA + row * 128 + swz128(row, ks * 64 + lk * 16));
      }
#pragma unroll
      for (int Nt = 0; Nt < 4; ++Nt) {
        const int n = wn * 64 + Nt * 16 + lr;
        const bf16x8 bv = *(const bf16x8*)(sB + n * 128 + swz128(n, ks * 64 + lk * 16));
#pragma unroll
        for (int Mt = 0; Mt < 4; ++Mt) acc[Mt][Nt] = MFMA(av[Mt], bv, acc[Mt][Nt]);
      }
    }
    __syncthreads();
  }
  // epilogue: +b2, quantize to fp8, store PROJ8, accumulate consistent x2
  float x2p[4][4];
#pragma unroll
  for (int m = 0; m < 4; ++m)
#pragma unroll
    for (int q = 0; q < 4; ++q) x2p[m][q] = 0.f;
#pragma unroll
  for (int Nt = 0; Nt < 4; ++Nt) {
    const int col = wn * 64 + Nt * 16 + lr;
    const float bias = b2[col];
#pragma unroll
    for (int Mt = 0; Mt < 4; ++Mt) {
      const size_t rowb = r0 + wm * 64 + Mt * 16 + lk * 4;
#pragma unroll
      for (int q = 0; q < 4; ++q) {
        const float p = acc[Mt][Nt][q] + bias;
        const unsigned char qb = f32_to_e4m3(p);
        PROJ8[(rowb + q) * 256 + col] = qb;
        const float d = e4m3_to_f32(qb);
        x2p[Mt][q] += d * d;
      }
    }
  }
#pragma unroll
  for (int Mt = 0; Mt < 4; ++Mt)
#pragma unroll
    for (int q = 0; q < 4; ++q) {
      float v = x2p[Mt][q];
      v += __shfl_xor(v, 1); v += __shfl_xor(v, 2);
      v += __shfl_xor(v, 4); v += __shfl_xor(v, 8);
      x2p[Mt][q] = v;
    }
  __syncthreads();
  if (lr == 0) {
#pragma unroll
    for (int Mt = 0; Mt < 4; ++Mt)
#pragma unroll
      for (int q = 0; q < 4; ++q)
        sX2[wn * 128 + wm * 64 + Mt * 16 + lk * 4 + q] = x2p[Mt][q];
  }
  __syncthreads();
  if (tid < 128)
    X2[r0 + tid] = sX2[tid] + sX2[128 + tid] + sX2[256 + tid] + sX2[384 + tid];
}

// ---------------- dist (MX-fp8 32x32x64, LDS-free): 128 rows/block, grid 256 = 1 block/CU.
// 8 waves = 4 bank-groups (32 banks each) x 2 row-halves (64 rows each). Per wave: A = 64
// VGPR, B dbuf 64, acc 32, minv 32 -> ~206 regs (50 slack; r8/r10 spill lesson). Half the
// MFMA instructions per FLOP vs 16x16 (issue-cadence hypothesis from r7/r9/r14 fits).
// Fragment layout validated by r3's 32x32 bf16 kernel (k-spans scaled x4 for fp8 K=64).
__global__ __launch_bounds__(512, 2) void dist_kernel(const unsigned char* __restrict__ PROJ8,
                                                      const unsigned char* __restrict__ SB8,
                                                      const float* __restrict__ m2g,
                                                      const float* __restrict__ X2,
                                                      float* __restrict__ out) {
  __shared__ float minbuf[512];  // [4 bg][128 rows]

  const int tid = threadIdx.x;
  const int w = tid >> 6, lane = tid & 63;
  const int l31 = lane & 31, hi = lane >> 5;
  const int bg = w & 3, rh = w >> 2;
  const size_t r0 = (size_t)blockIdx.x * 128;

  // A[rt][kc]: rows r0 + rh*64 + rt*32 + l31, k = kc*64 + hi*32 + [0,32)
  i32x8 A[2][4];
#pragma unroll
  for (int rt = 0; rt < 2; ++rt)
#pragma unroll
    for (int kc = 0; kc < 4; ++kc)
      A[rt][kc] =
          *(const i32x8*)(PROJ8 + (r0 + rh * 64 + rt * 32 + l31) * 256 + kc * 64 + hi * 32);

  const char* sb = (const char*)SB8 + (size_t)bg * 8192 + lane * 32;  // + t*32768 + kc*2048
  const float* m2p = m2g + bg * 32 + l31;                             // + t*128

  f32x16 minv0, minv1;
#pragma unroll
  for (int r = 0; r < 16; ++r) { minv0[r] = 3.0e38f; minv1[r] = 3.0e38f; }

#define LOADT(B, MC, tt)                                                \
  do {                                                                  \
    _Pragma("unroll") for (int kc = 0; kc < 4; ++kc)                    \
      B[kc] = *(const i32x8*)(sb + (size_t)(tt) * 32768 + kc * 2048);   \
    MC = m2p[(tt) * 128];                                               \
  } while (0)

  // acc starts at m2[col]; SB8 = -2*bank, so acc ends at m2 - 2*<proj,bank>
#define COMPUTE(B, MC)                                                  \
  do {                                                                  \
    f32x16 acc0, acc1;                                                  \
    _Pragma("unroll") for (int r = 0; r < 16; ++r) {                    \
      acc0[r] = (MC); acc1[r] = (MC);                                   \
    }                                                                   \
    __builtin_amdgcn_s_setprio(1);                                      \
    _Pragma("unroll") for (int kc = 0; kc < 4; ++kc) {                  \
      acc0 = MFMAS32(A[0][kc], B[kc], acc0);                            \
      acc1 = MFMAS32(A[1][kc], B[kc], acc1);                            \
    }                                                                   \
    __builtin_amdgcn_s_setprio(0);                                      \
    _Pragma("unroll") for (int r = 0; r < 16; ++r) {                    \
      minv0[r] = fminf(minv0[r], acc0[r]);                              \
      minv1[r] = fminf(minv1[r], acc1[r]);                              \
    }                                                                   \
  } while (0)

  // prologue: tile 0 into slot a
  i32x8 Ba[4], Bb[4];
  float ma, mb;
  LOADT(Ba, ma, 0);

  for (int t = 0; t < 128; t += 2) {
    LOADT(Bb, mb, t + 1);
    COMPUTE(Ba, ma);
    LOADT(Ba, ma, t + 2);  // t=126 -> tile 128 (read-only pad)
    COMPUTE(Bb, mb);
  }
#undef LOADT
#undef COMPUTE

  // reduce min over the 32 bank-column lanes (l31); rows at (r&3)+8*(r>>2)+4*hi
#pragma unroll
  for (int r = 0; r < 16; ++r) {
    float v0 = minv0[r], v1 = minv1[r];
#pragma unroll
    for (int off = 1; off < 32; off <<= 1) {
      v0 = fminf(v0, __shfl_xor(v0, off));
      v1 = fminf(v1, __shfl_xor(v1, off));
    }
    minv0[r] = v0; minv1[r] = v1;
  }
  if (l31 == 0) {
#pragma unroll
    for (int r = 0; r < 16; ++r) {
      const int rowa = (r & 3) + 8 * (r >> 2) + 4 * hi;
      minbuf[bg * 128 + rh * 64 + rowa] = minv0[r];
      minbuf[bg * 128 + rh * 64 + 32 + rowa] = minv1[r];
    }
  }
  __syncthreads();
  if (tid < 128) {
    const float m = fminf(fminf(minbuf[tid], minbuf[128 + tid]),
                          fminf(minbuf[256 + tid], minbuf[384 + tid]));
    const float d2 = X2[r0 + tid] + m;
    out[r0 + tid] = sqrtf(fmaxf(d2, 0.f));
  }
}

extern "C" void kernel_launch(void* const* d_in, const int* in_sizes, int n_in,
                              void* d_out, int out_size, void* d_ws, size_t ws_size,
                              hipStream_t stream) {
  const float* F = (const float*)d_in[0];
  const float* W1 = (const float*)d_in[1];
  const float* b1 = (const float*)d_in[2];
  const float* W2 = (const float*)d_in[3];
  const float* b2 = (const float*)d_in[4];
  const float* bank = (const float*)d_in[5];
  float* out = (float*)d_out;

  char* ws = (char*)d_ws;
  unsigned char* SB8 = (unsigned char*)(ws + 0);   // 4,194,304 B + 131,072 pad (read-only pad)
  float* m2 = (float*)(ws + 4325376);              //    65,536 B +   2,048 pad (read-only pad)
  bf16* W1t = (bf16*)(ws + 4392960);               // 1,048,576 B
  bf16* W2t = (bf16*)(ws + 5441536);               //   262,144 B
  bf16* H = (bf16*)(ws + 5703680);                 // 33,554,432 B
  unsigned char* PROJ8 = (unsigned char*)(ws + 39258112);  // 8,388,608 B
  float* X2 = (float*)(ws + 47646720);             //   131,072 B -> total 47,777,792 B

  prep_all<<<6656, 256, 0, stream>>>(W1, W2, bank, W1t, W2t, SB8, m2);
  mlp1_kernel<<<256, 512, 0, stream>>>(F, W1t, b1, H);
  mlp2_kernel<<<256, 512, 0, stream>>>(H, W2t, b2, PROJ8, X2);
  dist_kernel<<<256, 512, 0, stream>>>(PROJ8, SB8, m2, X2, out);
}